// Round 4
// baseline (814.759 us; speedup 1.0000x reference)
//
#include <hip/hip_runtime.h>

#define N_NODES 100000
#define N_EDGES 1600000
#define NPB 128          // nodes per bucket (dst >> 7)
#define NB ((N_NODES + NPB - 1) / NPB)   // 782 buckets
#define CAP 4096         // LDS edge capacity per bucket (mean 2048, sigma ~45)

// ---------------- degree histogram (int) ----------------

__global__ void deg_kernel(const int* __restrict__ dst, int* __restrict__ deg, int E) {
    int e = blockIdx.x * blockDim.x + threadIdx.x;
    if (e < E) atomicAdd(&deg[dst[e]], 1);
}

// ---------------- exclusive scan of deg -> rowptr (+ fused dis) ----------------

__global__ void scan_block_kernel(const int* __restrict__ deg, int* __restrict__ excl,
                                  int* __restrict__ bsums, float* __restrict__ dis, int n) {
    __shared__ int sh[256];
    const int base = blockIdx.x * 1024 + threadIdx.x * 4;
    int v0 = (base + 0 < n) ? deg[base + 0] : 0;
    int v1 = (base + 1 < n) ? deg[base + 1] : 0;
    int v2 = (base + 2 < n) ? deg[base + 2] : 0;
    int v3 = (base + 3 < n) ? deg[base + 3] : 0;
    // fused: dis = rsqrt(deg+1)
    if (base + 0 < n) dis[base + 0] = rsqrtf((float)v0 + 1.0f);
    if (base + 1 < n) dis[base + 1] = rsqrtf((float)v1 + 1.0f);
    if (base + 2 < n) dis[base + 2] = rsqrtf((float)v2 + 1.0f);
    if (base + 3 < n) dis[base + 3] = rsqrtf((float)v3 + 1.0f);
    int s = v0 + v1 + v2 + v3;
    sh[threadIdx.x] = s;
    __syncthreads();
    for (int off = 1; off < 256; off <<= 1) {
        int t = (threadIdx.x >= off) ? sh[threadIdx.x - off] : 0;
        __syncthreads();
        sh[threadIdx.x] += t;
        __syncthreads();
    }
    int run = sh[threadIdx.x] - s;
    if (threadIdx.x == 255) bsums[blockIdx.x] = sh[255];
    if (base + 0 < n) excl[base + 0] = run;  run += v0;
    if (base + 1 < n) excl[base + 1] = run;  run += v1;
    if (base + 2 < n) excl[base + 2] = run;  run += v2;
    if (base + 3 < n) excl[base + 3] = run;
}

__global__ void scan_sums_kernel(int* __restrict__ bsums, int nb) {
    __shared__ int sh[128];
    int v = (threadIdx.x < nb) ? bsums[threadIdx.x] : 0;
    sh[threadIdx.x] = v;
    __syncthreads();
    for (int off = 1; off < 128; off <<= 1) {
        int t = (threadIdx.x >= off) ? sh[threadIdx.x - off] : 0;
        __syncthreads();
        sh[threadIdx.x] += t;
        __syncthreads();
    }
    if (threadIdx.x < nb) bsums[threadIdx.x] = sh[threadIdx.x] - v;
}

// finalize rowptr (+ fused bucket cursor init: cursor[b] = rowptr[b*NPB])
__global__ void add_offsets_kernel(int* __restrict__ rowptr, const int* __restrict__ bsums,
                                   int* __restrict__ cursor, int n) {
    int i = blockIdx.x * blockDim.x + threadIdx.x;
    if (i < n) {
        int r = rowptr[i] + bsums[i >> 10];
        rowptr[i] = r;
        if ((i & (NPB - 1)) == 0) cursor[i >> 7] = r;
    }
}

// ---------------- pass B: coarse bin by dst>>7; sequential positions per bucket ----------------
// tmp payload: .x = src | (local_dst << 20), .y = norm bits

__global__ void binfill_kernel(const int* __restrict__ src, const int* __restrict__ dst,
                               const float* __restrict__ dis, int* __restrict__ cursor,
                               int2* __restrict__ tmp, int E) {
    int e = blockIdx.x * blockDim.x + threadIdx.x;
    if (e >= E) return;
    int s = src[e];
    int d = dst[e];
    float nm = dis[s] * dis[d];
    int pos = atomicAdd(&cursor[d >> 7], 1);
    tmp[pos] = make_int2(s | ((d & (NPB - 1)) << 20), __float_as_int(nm));
}

// ---------------- pass C: sort within bucket via LDS; coalesced final write ----------------

__global__ void __launch_bounds__(256) sort_bucket_kernel(const int2* __restrict__ tmp,
                                                          int2* __restrict__ edges,
                                                          const int* __restrict__ rowptr,
                                                          int n, int E) {
    const int b = blockIdx.x;
    const int d0 = b * NPB;
    if (d0 >= n) return;
    const int d1 = min(d0 + NPB, n);
    const int base = rowptr[d0];
    const int end  = (d1 < n) ? rowptr[d1] : E;
    const int count = end - base;

    __shared__ int2 buf[CAP];
    __shared__ int fillc[NPB];
    __shared__ int rp[NPB];
    for (int j = threadIdx.x; j < NPB; j += blockDim.x) {
        fillc[j] = 0;
        rp[j] = (d0 + j < n) ? rowptr[d0 + j] - base : 0;
    }
    __syncthreads();

    if (count <= CAP) {
        for (int t = threadIdx.x; t < count; t += blockDim.x) {
            int2 e = tmp[base + t];
            int ld = e.x >> 20;
            int s  = e.x & 0xFFFFF;
            int pos = rp[ld] + atomicAdd(&fillc[ld], 1);
            buf[pos] = make_int2(s, e.y);
        }
        __syncthreads();
        for (int t = threadIdx.x; t < count; t += blockDim.x) edges[base + t] = buf[t];
    } else {
        // fallback (statistically unreachable): direct global scatter
        for (int t = threadIdx.x; t < count; t += blockDim.x) {
            int2 e = tmp[base + t];
            int ld = e.x >> 20;
            int s  = e.x & 0xFFFFF;
            int pos = rp[ld] + atomicAdd(&fillc[ld], 1);
            edges[base + pos] = make_int2(s, e.y);
        }
    }
}

// ---------------- all 3 weight transposes in one launch ----------------

__global__ void transpose_all_kernel(const float* __restrict__ W0, const float* __restrict__ W1,
                                     const float* __restrict__ W2, float* __restrict__ wt0,
                                     float* __restrict__ wt1, float* __restrict__ wt2) {
    int i = blockIdx.x * blockDim.x + threadIdx.x;
    if (i < 8192)       { int k = i / 64, c = i % 64;                 wt0[c * 128 + k] = W0[i]; }
    else if (i < 12288) { int j = i - 8192;  int k = j / 64, c = j % 64; wt1[c * 64 + k] = W1[j]; }
    else if (i < 14336) { int j = i - 12288; int k = j / 32, c = j % 32; wt2[c * 64 + k] = W2[j]; }
}

// ---------------- dense GEMM: y[n,DOUT] = x[n,DIN] @ W[DIN,DOUT] ----------------

template <int DIN, int DOUT>
__global__ void __launch_bounds__(256) gemm_kernel(const float* __restrict__ x,
                                                   const float* __restrict__ Wt,
                                                   float* __restrict__ y, int n) {
    constexpr int TPR  = DOUT / 4;
    constexpr int ROWS = 256 / TPR;
    constexpr int WS   = DIN + 4;

    __shared__ float Wl[DOUT * WS];
    __shared__ float Xl[ROWS * WS];

    for (int i = 4 * threadIdx.x; i < DIN * DOUT; i += 1024) {
        float4 v = *(const float4*)&Wt[i];
        int c = i / DIN, k = i % DIN;
        *(float4*)&Wl[c * WS + k] = v;
    }
    const int row0 = blockIdx.x * ROWS;
    for (int i = 4 * threadIdx.x; i < ROWS * DIN; i += 1024) {
        int r = i / DIN, k = i % DIN;
        float4 v = make_float4(0.f, 0.f, 0.f, 0.f);
        if (row0 + r < n) v = *(const float4*)&x[(long)(row0 + r) * DIN + k];
        *(float4*)&Xl[r * WS + k] = v;
    }
    __syncthreads();

    const int lrow = threadIdx.x / TPR;
    const int c0   = threadIdx.x % TPR;
    const int row  = row0 + lrow;
    if (row >= n) return;

    float acc0 = 0.f, acc1 = 0.f, acc2 = 0.f, acc3 = 0.f;
    const float* xr = &Xl[lrow * WS];
    const float* w0 = &Wl[(c0 + 0 * TPR) * WS];
    const float* w1 = &Wl[(c0 + 1 * TPR) * WS];
    const float* w2 = &Wl[(c0 + 2 * TPR) * WS];
    const float* w3 = &Wl[(c0 + 3 * TPR) * WS];

#pragma unroll 4
    for (int k = 0; k < DIN; k += 4) {
        float4 xv = *(const float4*)&xr[k];
        float4 a = *(const float4*)&w0[k];
        float4 b = *(const float4*)&w1[k];
        float4 c = *(const float4*)&w2[k];
        float4 d = *(const float4*)&w3[k];
        acc0 += xv.x * a.x + xv.y * a.y + xv.z * a.z + xv.w * a.w;
        acc1 += xv.x * b.x + xv.y * b.y + xv.z * b.z + xv.w * b.w;
        acc2 += xv.x * c.x + xv.y * c.y + xv.z * c.z + xv.w * c.w;
        acc3 += xv.x * d.x + xv.y * d.y + xv.z * d.z + xv.w * d.w;
    }

    float* yr = &y[(long)row * DOUT];
    yr[c0 + 0 * TPR] = acc0;
    yr[c0 + 1 * TPR] = acc1;
    yr[c0 + 2 * TPR] = acc2;
    yr[c0 + 3 * TPR] = acc3;
}

// ---------------- gather, DOUT=64, float2 per lane (2 nodes per wave) ----------------

template <bool RELU>
__global__ void gather2_kernel(const int* __restrict__ rowptr, const int* __restrict__ deg,
                               const int2* __restrict__ edges, const float* __restrict__ y,
                               const float* __restrict__ dis, const float* __restrict__ b,
                               float* __restrict__ out, int n) {
    const int node = blockIdx.x * 8 + (threadIdx.x >> 5);
    const int c = (threadIdx.x & 31) * 2;
    if (node >= n) return;

    const float di = dis[node];
    float2 yv = *(const float2*)&y[(long)node * 64 + c];
    float ax = yv.x * di * di + b[c];
    float ay = yv.y * di * di + b[c + 1];

    int k = rowptr[node];
    const int end = k + deg[node];
    for (; k + 4 <= end; k += 4) {
        int2 e0 = edges[k], e1 = edges[k + 1], e2 = edges[k + 2], e3 = edges[k + 3];
        float2 v0 = *(const float2*)&y[(long)e0.x * 64 + c];
        float2 v1 = *(const float2*)&y[(long)e1.x * 64 + c];
        float2 v2 = *(const float2*)&y[(long)e2.x * 64 + c];
        float2 v3 = *(const float2*)&y[(long)e3.x * 64 + c];
        ax += v0.x * __int_as_float(e0.y); ay += v0.y * __int_as_float(e0.y);
        ax += v1.x * __int_as_float(e1.y); ay += v1.y * __int_as_float(e1.y);
        ax += v2.x * __int_as_float(e2.y); ay += v2.y * __int_as_float(e2.y);
        ax += v3.x * __int_as_float(e3.y); ay += v3.y * __int_as_float(e3.y);
    }
    for (; k < end; ++k) {
        int2 e = edges[k];
        float2 v = *(const float2*)&y[(long)e.x * 64 + c];
        ax += v.x * __int_as_float(e.y); ay += v.y * __int_as_float(e.y);
    }

    if (RELU) { ax = fmaxf(ax, 0.0f); ay = fmaxf(ay, 0.0f); }
    *(float2*)&out[(long)node * 64 + c] = make_float2(ax, ay);
}

// ---------------- gather, scalar lane=col (used for DOUT=32) ----------------

template <int DOUT, bool RELU>
__global__ void gather_kernel(const int* __restrict__ rowptr, const int* __restrict__ deg,
                              const int2* __restrict__ edges, const float* __restrict__ y,
                              const float* __restrict__ dis, const float* __restrict__ b,
                              float* __restrict__ out, int n) {
    const int node = blockIdx.x * (blockDim.x / DOUT) + threadIdx.x / DOUT;
    const int c = threadIdx.x % DOUT;
    if (node >= n) return;

    const float di = dis[node];
    float acc = y[(long)node * DOUT + c] * di * di + b[c];

    int k = rowptr[node];
    const int end = k + deg[node];
    for (; k + 4 <= end; k += 4) {
        int2 e0 = edges[k], e1 = edges[k + 1], e2 = edges[k + 2], e3 = edges[k + 3];
        float v0 = y[(long)e0.x * DOUT + c];
        float v1 = y[(long)e1.x * DOUT + c];
        float v2 = y[(long)e2.x * DOUT + c];
        float v3 = y[(long)e3.x * DOUT + c];
        acc += v0 * __int_as_float(e0.y);
        acc += v1 * __int_as_float(e1.y);
        acc += v2 * __int_as_float(e2.y);
        acc += v3 * __int_as_float(e3.y);
    }
    for (; k < end; ++k) {
        int2 e = edges[k];
        acc += y[(long)e.x * DOUT + c] * __int_as_float(e.y);
    }

    if (RELU) acc = fmaxf(acc, 0.0f);
    out[(long)node * DOUT + c] = acc;
}

// ---------------- launch ----------------

extern "C" void kernel_launch(void* const* d_in, const int* in_sizes, int n_in,
                              void* d_out, int out_size, void* d_ws, size_t ws_size,
                              hipStream_t stream) {
    const float* features = (const float*)d_in[0];
    const int*   ei       = (const int*)d_in[1];
    const float* W0 = (const float*)d_in[2];
    const float* b0 = (const float*)d_in[3];
    const float* W1 = (const float*)d_in[4];
    const float* b1 = (const float*)d_in[5];
    const float* W2 = (const float*)d_in[6];
    const float* b2 = (const float*)d_in[7];

    const int* src = ei;             // edge_index[0]
    const int* dst = ei + N_EDGES;   // edge_index[1]

    const int n = N_NODES;
    const int E = N_EDGES;
    const int nb = (n + 1023) / 1024;

    // workspace layout (int slots from d_ws)
    int*   deg    = (int*)d_ws;                          // [0, 131072)
    float* dis    = (float*)d_ws + 131072;               // [131072, 262144)
    int*   rowptr = (int*)d_ws + 262144;                 // [262144, 393216)
    int*   cursor = (int*)d_ws + 393216;                 // [393216, 394240)
    int*   bsums  = (int*)d_ws + 394240;                 // [394240, 395264)
    int2*  edges  = (int2*)((int*)d_ws + 395264);        // 2*E ints
    float* bufA   = (float*)d_ws + 395264 + 2 * N_EDGES; // N*64 (also pass-B staging)
    float* bufB   = bufA + (size_t)N_NODES * 64;         // N*64
    float* wt0    = bufB + (size_t)N_NODES * 64;         // 128*64
    float* wt1    = wt0 + 128 * 64;                      // 64*64
    float* wt2    = wt1 + 64 * 64;                       // 64*32
    float* outf   = (float*)d_out;                       // N*32
    int2*  tmp    = (int2*)bufA;                         // staging for binfill

    // ---- CSR build + weight transposes ----
    hipMemsetAsync(deg, 0, (size_t)n * sizeof(int), stream);
    deg_kernel<<<(E + 255) / 256, 256, 0, stream>>>(dst, deg, E);
    scan_block_kernel<<<nb, 256, 0, stream>>>(deg, rowptr, bsums, dis, n);
    scan_sums_kernel<<<1, 128, 0, stream>>>(bsums, nb);
    add_offsets_kernel<<<(n + 255) / 256, 256, 0, stream>>>(rowptr, bsums, cursor, n);
    binfill_kernel<<<(E + 255) / 256, 256, 0, stream>>>(src, dst, dis, cursor, tmp, E);
    sort_bucket_kernel<<<NB, 256, 0, stream>>>(tmp, edges, rowptr, n, E);
    transpose_all_kernel<<<56, 256, 0, stream>>>(W0, W1, W2, wt0, wt1, wt2);

    // ---- layer 0: 128 -> 64, ReLU ----
    gemm_kernel<128, 64><<<(n + 15) / 16, 256, 0, stream>>>(features, wt0, bufA, n);
    gather2_kernel<true><<<(n + 7) / 8, 256, 0, stream>>>(rowptr, deg, edges, bufA, dis, b0, bufB, n);

    // ---- layer 1: 64 -> 64, ReLU ----
    gemm_kernel<64, 64><<<(n + 15) / 16, 256, 0, stream>>>(bufB, wt1, bufA, n);
    gather2_kernel<true><<<(n + 7) / 8, 256, 0, stream>>>(rowptr, deg, edges, bufA, dis, b1, bufB, n);

    // ---- layer 2: 64 -> 32, no ReLU ----
    gemm_kernel<64, 32><<<(n + 31) / 32, 256, 0, stream>>>(bufB, wt2, bufA, n);
    gather_kernel<32, false><<<(n + 7) / 8, 256, 0, stream>>>(rowptr, deg, edges, bufA, dis, b2, outf, n);
}

// Round 5
// 445.198 us; speedup vs baseline: 1.8301x; 1.8301x over previous
//
#include <hip/hip_runtime.h>
#include <hip/hip_fp16.h>

#define N_NODES 100000
#define N_EDGES 1600000

// ---------------- degree histogram (int) ----------------

__global__ void deg_kernel(const int* __restrict__ dst, int* __restrict__ deg, int E) {
    int e = blockIdx.x * blockDim.x + threadIdx.x;
    if (e < E) atomicAdd(&deg[dst[e]], 1);
}

// ---------------- exclusive scan of deg -> rowptr (+ fused dis) ----------------

__global__ void scan_block_kernel(const int* __restrict__ deg, int* __restrict__ excl,
                                  int* __restrict__ bsums, float* __restrict__ dis, int n) {
    __shared__ int sh[256];
    const int base = blockIdx.x * 1024 + threadIdx.x * 4;
    int v0 = (base + 0 < n) ? deg[base + 0] : 0;
    int v1 = (base + 1 < n) ? deg[base + 1] : 0;
    int v2 = (base + 2 < n) ? deg[base + 2] : 0;
    int v3 = (base + 3 < n) ? deg[base + 3] : 0;
    if (base + 0 < n) dis[base + 0] = rsqrtf((float)v0 + 1.0f);
    if (base + 1 < n) dis[base + 1] = rsqrtf((float)v1 + 1.0f);
    if (base + 2 < n) dis[base + 2] = rsqrtf((float)v2 + 1.0f);
    if (base + 3 < n) dis[base + 3] = rsqrtf((float)v3 + 1.0f);
    int s = v0 + v1 + v2 + v3;
    sh[threadIdx.x] = s;
    __syncthreads();
    for (int off = 1; off < 256; off <<= 1) {
        int t = (threadIdx.x >= off) ? sh[threadIdx.x - off] : 0;
        __syncthreads();
        sh[threadIdx.x] += t;
        __syncthreads();
    }
    int run = sh[threadIdx.x] - s;
    if (threadIdx.x == 255) bsums[blockIdx.x] = sh[255];
    if (base + 0 < n) excl[base + 0] = run;  run += v0;
    if (base + 1 < n) excl[base + 1] = run;  run += v1;
    if (base + 2 < n) excl[base + 2] = run;  run += v2;
    if (base + 3 < n) excl[base + 3] = run;
}

__global__ void scan_sums_kernel(int* __restrict__ bsums, int nb) {
    __shared__ int sh[128];
    int v = (threadIdx.x < nb) ? bsums[threadIdx.x] : 0;
    sh[threadIdx.x] = v;
    __syncthreads();
    for (int off = 1; off < 128; off <<= 1) {
        int t = (threadIdx.x >= off) ? sh[threadIdx.x - off] : 0;
        __syncthreads();
        sh[threadIdx.x] += t;
        __syncthreads();
    }
    if (threadIdx.x < nb) bsums[threadIdx.x] = sh[threadIdx.x] - v;
}

__global__ void add_offsets_kernel(int* __restrict__ rowptr, const int* __restrict__ bsums, int n) {
    int i = blockIdx.x * blockDim.x + threadIdx.x;
    if (i < n) rowptr[i] += bsums[i >> 10];
}

// ---------------- fill CSR: edges sorted by dst, payload = (src, norm) ----------------
// (round-3 version: atomics spread over 100K fill counters — low contention)

__global__ void fill_kernel(const int* __restrict__ src, const int* __restrict__ dst,
                            const int* __restrict__ rowptr, int* __restrict__ fill,
                            const float* __restrict__ dis, int2* __restrict__ edges, int E) {
    int e = blockIdx.x * blockDim.x + threadIdx.x;
    if (e >= E) return;
    int s = src[e];
    int d = dst[e];
    int pos = rowptr[d] + atomicAdd(&fill[d], 1);
    float nm = dis[s] * dis[d];
    edges[pos] = make_int2(s, __float_as_int(nm));
}

// ---------------- all 3 weight transposes in one launch ----------------

__global__ void transpose_all_kernel(const float* __restrict__ W0, const float* __restrict__ W1,
                                     const float* __restrict__ W2, float* __restrict__ wt0,
                                     float* __restrict__ wt1, float* __restrict__ wt2) {
    int i = blockIdx.x * blockDim.x + threadIdx.x;
    if (i < 8192)       { int k = i / 64, c = i % 64;                 wt0[c * 128 + k] = W0[i]; }
    else if (i < 12288) { int j = i - 8192;  int k = j / 64, c = j % 64; wt1[c * 64 + k] = W1[j]; }
    else if (i < 14336) { int j = i - 12288; int k = j / 32, c = j % 32; wt2[c * 64 + k] = W2[j]; }
}

// ---------------- dense GEMM: y16[n,DOUT] = x[n,DIN] @ W[DIN,DOUT], fp16 output ----------------

template <int DIN, int DOUT>
__global__ void __launch_bounds__(256) gemm_kernel(const float* __restrict__ x,
                                                   const float* __restrict__ Wt,
                                                   __half* __restrict__ y, int n) {
    constexpr int TPR  = DOUT / 4;
    constexpr int ROWS = 256 / TPR;
    constexpr int WS   = DIN + 4;

    __shared__ float Wl[DOUT * WS];
    __shared__ float Xl[ROWS * WS];

    for (int i = 4 * threadIdx.x; i < DIN * DOUT; i += 1024) {
        float4 v = *(const float4*)&Wt[i];
        int c = i / DIN, k = i % DIN;
        *(float4*)&Wl[c * WS + k] = v;
    }
    const int row0 = blockIdx.x * ROWS;
    for (int i = 4 * threadIdx.x; i < ROWS * DIN; i += 1024) {
        int r = i / DIN, k = i % DIN;
        float4 v = make_float4(0.f, 0.f, 0.f, 0.f);
        if (row0 + r < n) v = *(const float4*)&x[(long)(row0 + r) * DIN + k];
        *(float4*)&Xl[r * WS + k] = v;
    }
    __syncthreads();

    const int lrow = threadIdx.x / TPR;
    const int c0   = threadIdx.x % TPR;
    const int row  = row0 + lrow;
    if (row >= n) return;

    float acc0 = 0.f, acc1 = 0.f, acc2 = 0.f, acc3 = 0.f;
    const float* xr = &Xl[lrow * WS];
    const float* w0 = &Wl[(c0 + 0 * TPR) * WS];
    const float* w1 = &Wl[(c0 + 1 * TPR) * WS];
    const float* w2 = &Wl[(c0 + 2 * TPR) * WS];
    const float* w3 = &Wl[(c0 + 3 * TPR) * WS];

#pragma unroll 4
    for (int k = 0; k < DIN; k += 4) {
        float4 xv = *(const float4*)&xr[k];
        float4 a = *(const float4*)&w0[k];
        float4 b = *(const float4*)&w1[k];
        float4 c = *(const float4*)&w2[k];
        float4 d = *(const float4*)&w3[k];
        acc0 += xv.x * a.x + xv.y * a.y + xv.z * a.z + xv.w * a.w;
        acc1 += xv.x * b.x + xv.y * b.y + xv.z * b.z + xv.w * b.w;
        acc2 += xv.x * c.x + xv.y * c.y + xv.z * c.z + xv.w * c.w;
        acc3 += xv.x * d.x + xv.y * d.y + xv.z * d.z + xv.w * d.w;
    }

    __half* yr = &y[(long)row * DOUT];
    yr[c0 + 0 * TPR] = __float2half(acc0);
    yr[c0 + 1 * TPR] = __float2half(acc1);
    yr[c0 + 2 * TPR] = __float2half(acc2);
    yr[c0 + 3 * TPR] = __float2half(acc3);
}

// ---------------- gather DOUT=64: 2 nodes/wave, half2 per lane, fp32 out ----------------

template <bool RELU>
__global__ void gather2h_kernel(const int* __restrict__ rowptr, const int* __restrict__ deg,
                                const int2* __restrict__ edges, const __half* __restrict__ y,
                                const float* __restrict__ dis, const float* __restrict__ b,
                                float* __restrict__ out, int n) {
    const int node = blockIdx.x * 8 + (threadIdx.x >> 5);
    const int c = (threadIdx.x & 31) * 2;
    if (node >= n) return;

    const float di = dis[node];
    float2 yv = __half22float2(*(const __half2*)&y[(long)node * 64 + c]);
    float ax = yv.x * di * di + b[c];
    float ay = yv.y * di * di + b[c + 1];

    int k = rowptr[node];
    const int end = k + deg[node];
    for (; k + 4 <= end; k += 4) {
        int2 e0 = edges[k], e1 = edges[k + 1], e2 = edges[k + 2], e3 = edges[k + 3];
        float2 v0 = __half22float2(*(const __half2*)&y[(long)e0.x * 64 + c]);
        float2 v1 = __half22float2(*(const __half2*)&y[(long)e1.x * 64 + c]);
        float2 v2 = __half22float2(*(const __half2*)&y[(long)e2.x * 64 + c]);
        float2 v3 = __half22float2(*(const __half2*)&y[(long)e3.x * 64 + c]);
        ax += v0.x * __int_as_float(e0.y); ay += v0.y * __int_as_float(e0.y);
        ax += v1.x * __int_as_float(e1.y); ay += v1.y * __int_as_float(e1.y);
        ax += v2.x * __int_as_float(e2.y); ay += v2.y * __int_as_float(e2.y);
        ax += v3.x * __int_as_float(e3.y); ay += v3.y * __int_as_float(e3.y);
    }
    for (; k < end; ++k) {
        int2 e = edges[k];
        float2 v = __half22float2(*(const __half2*)&y[(long)e.x * 64 + c]);
        ax += v.x * __int_as_float(e.y); ay += v.y * __int_as_float(e.y);
    }

    if (RELU) { ax = fmaxf(ax, 0.0f); ay = fmaxf(ay, 0.0f); }
    *(float2*)&out[(long)node * 64 + c] = make_float2(ax, ay);
}

// ---------------- gather DOUT=32: 4 nodes/wave, half2 per lane, fp32 out ----------------

template <bool RELU>
__global__ void gather4h_kernel(const int* __restrict__ rowptr, const int* __restrict__ deg,
                                const int2* __restrict__ edges, const __half* __restrict__ y,
                                const float* __restrict__ dis, const float* __restrict__ b,
                                float* __restrict__ out, int n) {
    const int node = blockIdx.x * 16 + (threadIdx.x >> 4);
    const int c = (threadIdx.x & 15) * 2;
    if (node >= n) return;

    const float di = dis[node];
    float2 yv = __half22float2(*(const __half2*)&y[(long)node * 32 + c]);
    float ax = yv.x * di * di + b[c];
    float ay = yv.y * di * di + b[c + 1];

    int k = rowptr[node];
    const int end = k + deg[node];
    for (; k + 4 <= end; k += 4) {
        int2 e0 = edges[k], e1 = edges[k + 1], e2 = edges[k + 2], e3 = edges[k + 3];
        float2 v0 = __half22float2(*(const __half2*)&y[(long)e0.x * 32 + c]);
        float2 v1 = __half22float2(*(const __half2*)&y[(long)e1.x * 32 + c]);
        float2 v2 = __half22float2(*(const __half2*)&y[(long)e2.x * 32 + c]);
        float2 v3 = __half22float2(*(const __half2*)&y[(long)e3.x * 32 + c]);
        ax += v0.x * __int_as_float(e0.y); ay += v0.y * __int_as_float(e0.y);
        ax += v1.x * __int_as_float(e1.y); ay += v1.y * __int_as_float(e1.y);
        ax += v2.x * __int_as_float(e2.y); ay += v2.y * __int_as_float(e2.y);
        ax += v3.x * __int_as_float(e3.y); ay += v3.y * __int_as_float(e3.y);
    }
    for (; k < end; ++k) {
        int2 e = edges[k];
        float2 v = __half22float2(*(const __half2*)&y[(long)e.x * 32 + c]);
        ax += v.x * __int_as_float(e.y); ay += v.y * __int_as_float(e.y);
    }

    if (RELU) { ax = fmaxf(ax, 0.0f); ay = fmaxf(ay, 0.0f); }
    *(float2*)&out[(long)node * 32 + c] = make_float2(ax, ay);
}

// ---------------- launch ----------------

extern "C" void kernel_launch(void* const* d_in, const int* in_sizes, int n_in,
                              void* d_out, int out_size, void* d_ws, size_t ws_size,
                              hipStream_t stream) {
    const float* features = (const float*)d_in[0];
    const int*   ei       = (const int*)d_in[1];
    const float* W0 = (const float*)d_in[2];
    const float* b0 = (const float*)d_in[3];
    const float* W1 = (const float*)d_in[4];
    const float* b1 = (const float*)d_in[5];
    const float* W2 = (const float*)d_in[6];
    const float* b2 = (const float*)d_in[7];

    const int* src = ei;             // edge_index[0]
    const int* dst = ei + N_EDGES;   // edge_index[1]

    const int n = N_NODES;
    const int E = N_EDGES;
    const int nb = (n + 1023) / 1024;

    // workspace layout (int slots from d_ws)
    int*   deg    = (int*)d_ws;                          // [0, 131072)
    float* dis    = (float*)d_ws + 131072;               // [131072, 262144)
    int*   rowptr = (int*)d_ws + 262144;                 // [262144, 393216)
    int*   fill   = (int*)d_ws + 393216;                 // [393216, 524288)
    int*   bsums  = (int*)d_ws + 524288;                 // [524288, 525312)
    int2*  edges  = (int2*)((int*)d_ws + 525312);        // 2*E ints
    __half* yh    = (__half*)((int*)d_ws + 525312 + 2 * N_EDGES);  // N*64 halves (fits in N*32 ints)
    float* act    = (float*)d_ws + 525312 + 2 * N_EDGES + 32 * N_NODES;  // N*64 floats
    float* wt0    = act + (size_t)N_NODES * 64;          // 128*64
    float* wt1    = wt0 + 128 * 64;                      // 64*64
    float* wt2    = wt1 + 64 * 64;                       // 64*32
    float* outf   = (float*)d_out;                       // N*32

    // ---- CSR build + weight transposes (once per call, reused by all 3 layers) ----
    hipMemsetAsync(deg, 0, (size_t)n * sizeof(int), stream);
    hipMemsetAsync(fill, 0, (size_t)n * sizeof(int), stream);
    deg_kernel<<<(E + 255) / 256, 256, 0, stream>>>(dst, deg, E);
    scan_block_kernel<<<nb, 256, 0, stream>>>(deg, rowptr, bsums, dis, n);
    scan_sums_kernel<<<1, 128, 0, stream>>>(bsums, nb);
    add_offsets_kernel<<<(n + 255) / 256, 256, 0, stream>>>(rowptr, bsums, n);
    fill_kernel<<<(E + 255) / 256, 256, 0, stream>>>(src, dst, rowptr, fill, dis, edges, E);
    transpose_all_kernel<<<56, 256, 0, stream>>>(W0, W1, W2, wt0, wt1, wt2);

    // ---- layer 0: 128 -> 64, ReLU ----
    gemm_kernel<128, 64><<<(n + 15) / 16, 256, 0, stream>>>(features, wt0, yh, n);
    gather2h_kernel<true><<<(n + 7) / 8, 256, 0, stream>>>(rowptr, deg, edges, yh, dis, b0, act, n);

    // ---- layer 1: 64 -> 64, ReLU ----
    gemm_kernel<64, 64><<<(n + 15) / 16, 256, 0, stream>>>(act, wt1, yh, n);
    gather2h_kernel<true><<<(n + 7) / 8, 256, 0, stream>>>(rowptr, deg, edges, yh, dis, b1, act, n);

    // ---- layer 2: 64 -> 32, no ReLU ----
    gemm_kernel<64, 32><<<(n + 31) / 32, 256, 0, stream>>>(act, wt2, yh, n);
    gather4h_kernel<false><<<(n + 15) / 16, 256, 0, stream>>>(rowptr, deg, edges, yh, dis, b2, outf, n);
}

// Round 9
// 374.031 us; speedup vs baseline: 2.1783x; 1.1903x over previous
//
#include <hip/hip_runtime.h>
#include <hip/hip_fp16.h>

#define N_NODES 100000
#define N_EDGES 1600000
#define NPB 128                                   // nodes per dst-bucket
#define NBK ((N_NODES + NPB - 1) / NPB)           // 782 buckets
#define FBLK 128                                  // fill blocks
#define EPB ((N_EDGES + FBLK - 1) / FBLK)         // 12500 edges per fill block
#define CAP 4096                                  // LDS capacity per bucket (mean 2046, sigma ~45)

// ---------------- pass 1: per-block bucket histograms (no global atomics) ----------------

__global__ void __launch_bounds__(256) hist_kernel(const int* __restrict__ dst, int* __restrict__ H) {
    __shared__ int h[NBK];
    for (int i = threadIdx.x; i < NBK; i += 256) h[i] = 0;
    __syncthreads();
    const int e0 = blockIdx.x * EPB;
    const int e1 = min(e0 + EPB, N_EDGES);
    for (int e = e0 + threadIdx.x; e < e1; e += 256) atomicAdd(&h[dst[e] >> 7], 1);
    __syncthreads();
    for (int i = threadIdx.x; i < NBK; i += 256) H[blockIdx.x * NBK + i] = h[i];
}

// ---------------- pass 2: H -> per-(block,bucket) bases + bucket ptrs ----------------

__global__ void __launch_bounds__(1024) basescan_kernel(int* __restrict__ H, int* __restrict__ bptr) {
    __shared__ int tot[1024];
    const int t = threadIdx.x;
    int run = 0;
    if (t < NBK) {
        for (int k = 0; k < FBLK; ++k) {
            int idx = k * NBK + t;
            int h = H[idx];
            H[idx] = run;           // exclusive over blocks, within bucket
            run += h;
        }
    }
    tot[t] = (t < NBK) ? run : 0;
    __syncthreads();
    for (int off = 1; off < 1024; off <<= 1) {
        int v = (t >= off) ? tot[t - off] : 0;
        __syncthreads();
        tot[t] += v;
        __syncthreads();
    }
    if (t < NBK) {
        int excl = tot[t] - run;    // exclusive bucket base
        bptr[t] = excl;
        for (int k = 0; k < FBLK; ++k) H[k * NBK + t] += excl;
    }
    if (t == 0) bptr[NBK] = N_EDGES;
}

// ---------------- pass 3: bin edges by bucket; 4B payload = src | (local_dst<<20) ----------------

__global__ void __launch_bounds__(256) binfill_kernel(const int* __restrict__ src, const int* __restrict__ dst,
                                                      const int* __restrict__ H, int* __restrict__ tmp) {
    __shared__ int cur[NBK];
    const int k = blockIdx.x;
    for (int i = threadIdx.x; i < NBK; i += 256) cur[i] = H[k * NBK + i];
    __syncthreads();
    const int e0 = k * EPB;
    const int e1 = min(e0 + EPB, N_EDGES);
    for (int e = e0 + threadIdx.x; e < e1; e += 256) {
        int s = src[e];
        int d = dst[e];
        int pos = atomicAdd(&cur[d >> 7], 1);      // LDS atomic only
        tmp[pos] = s | ((d & (NPB - 1)) << 20);
    }
}

// ---------------- pass 4: per-bucket degree recount (sequential reads, no global atomics) ----------------

__global__ void __launch_bounds__(256) degcnt_kernel(const int* __restrict__ tmp, const int* __restrict__ bptr,
                                                     int* __restrict__ deg, int n) {
    __shared__ int cnt[NPB];
    const int b = blockIdx.x;
    const int d0 = b * NPB;
    const int nd = min(NPB, n - d0);
    for (int i = threadIdx.x; i < NPB; i += 256) cnt[i] = 0;
    __syncthreads();
    const int e1 = bptr[b + 1];
    for (int e = bptr[b] + threadIdx.x; e < e1; e += 256) atomicAdd(&cnt[tmp[e] >> 20], 1);
    __syncthreads();
    for (int i = threadIdx.x; i < nd; i += 256) deg[d0 + i] = cnt[i];
}

// ---------------- exclusive scan of deg -> rowptr (+ fused dis) — validated r5 ----------------

__global__ void scan_block_kernel(const int* __restrict__ deg, int* __restrict__ excl,
                                  int* __restrict__ bsums, float* __restrict__ dis, int n) {
    __shared__ int sh[256];
    const int base = blockIdx.x * 1024 + threadIdx.x * 4;
    int v0 = (base + 0 < n) ? deg[base + 0] : 0;
    int v1 = (base + 1 < n) ? deg[base + 1] : 0;
    int v2 = (base + 2 < n) ? deg[base + 2] : 0;
    int v3 = (base + 3 < n) ? deg[base + 3] : 0;
    if (base + 0 < n) dis[base + 0] = rsqrtf((float)v0 + 1.0f);
    if (base + 1 < n) dis[base + 1] = rsqrtf((float)v1 + 1.0f);
    if (base + 2 < n) dis[base + 2] = rsqrtf((float)v2 + 1.0f);
    if (base + 3 < n) dis[base + 3] = rsqrtf((float)v3 + 1.0f);
    int s = v0 + v1 + v2 + v3;
    sh[threadIdx.x] = s;
    __syncthreads();
    for (int off = 1; off < 256; off <<= 1) {
        int t = (threadIdx.x >= off) ? sh[threadIdx.x - off] : 0;
        __syncthreads();
        sh[threadIdx.x] += t;
        __syncthreads();
    }
    int run = sh[threadIdx.x] - s;
    if (threadIdx.x == 255) bsums[blockIdx.x] = sh[255];
    if (base + 0 < n) excl[base + 0] = run;  run += v0;
    if (base + 1 < n) excl[base + 1] = run;  run += v1;
    if (base + 2 < n) excl[base + 2] = run;  run += v2;
    if (base + 3 < n) excl[base + 3] = run;
}

__global__ void scan_sums_kernel(int* __restrict__ bsums, int nb) {
    __shared__ int sh[128];
    int v = (threadIdx.x < nb) ? bsums[threadIdx.x] : 0;
    sh[threadIdx.x] = v;
    __syncthreads();
    for (int off = 1; off < 128; off <<= 1) {
        int t = (threadIdx.x >= off) ? sh[threadIdx.x - off] : 0;
        __syncthreads();
        sh[threadIdx.x] += t;
        __syncthreads();
    }
    if (threadIdx.x < nb) bsums[threadIdx.x] = sh[threadIdx.x] - v;
}

__global__ void add_offsets_kernel(int* __restrict__ rowptr, const int* __restrict__ bsums, int n) {
    int i = blockIdx.x * blockDim.x + threadIdx.x;
    if (i < n) rowptr[i] += bsums[i >> 10];
}

// ---------------- pass 5: r4-validated LDS sort -> per-node-sorted 4B src array ----------------

__global__ void __launch_bounds__(256) sortfin_kernel(const int* __restrict__ tmp, int* __restrict__ esrc,
                                                      const int* __restrict__ rowptr, const int* __restrict__ bptr,
                                                      int n) {
    __shared__ int buf[CAP];
    __shared__ int fillc[NPB];
    __shared__ int rp[NPB];
    const int b = blockIdx.x;
    const int d0 = b * NPB;
    const int base = bptr[b];
    const int end  = bptr[b + 1];
    const int count = end - base;
    for (int j = threadIdx.x; j < NPB; j += 256) {
        fillc[j] = 0;
        rp[j] = (d0 + j < n) ? rowptr[d0 + j] - base : 0;
    }
    __syncthreads();
    if (count <= CAP) {
        for (int t = threadIdx.x; t < count; t += 256) {
            int w = tmp[base + t];
            int ld = w >> 20;
            int pos = rp[ld] + atomicAdd(&fillc[ld], 1);
            buf[pos] = w & 0xFFFFF;
        }
        __syncthreads();
        for (int t = threadIdx.x; t < count; t += 256) esrc[base + t] = buf[t];
    } else {
        // statistically unreachable fallback
        for (int t = threadIdx.x; t < count; t += 256) {
            int w = tmp[base + t];
            int ld = w >> 20;
            int pos = rp[ld] + atomicAdd(&fillc[ld], 1);
            esrc[base + pos] = w & 0xFFFFF;
        }
    }
}

// ---------------- all 3 weight transposes in one launch ----------------

__global__ void transpose_all_kernel(const float* __restrict__ W0, const float* __restrict__ W1,
                                     const float* __restrict__ W2, float* __restrict__ wt0,
                                     float* __restrict__ wt1, float* __restrict__ wt2) {
    int i = blockIdx.x * blockDim.x + threadIdx.x;
    if (i < 8192)       { int k = i / 64, c = i % 64;                 wt0[c * 128 + k] = W0[i]; }
    else if (i < 12288) { int j = i - 8192;  int k = j / 64, c = j % 64; wt1[c * 64 + k] = W1[j]; }
    else if (i < 14336) { int j = i - 12288; int k = j / 32, c = j % 32; wt2[c * 64 + k] = W2[j]; }
}

// ---------------- dense GEMM (r5-validated + dis fold): ys = fp16(dis[row] * (x @ W)) ----------------

template <int DIN, int DOUT>
__global__ void __launch_bounds__(256) gemm_kernel(const float* __restrict__ x,
                                                   const float* __restrict__ Wt,
                                                   const float* __restrict__ dis,
                                                   __half* __restrict__ ys, int n) {
    constexpr int TPR  = DOUT / 4;
    constexpr int ROWS = 256 / TPR;
    constexpr int WS   = DIN + 4;

    __shared__ float Wl[DOUT * WS];
    __shared__ float Xl[ROWS * WS];

    for (int i = 4 * threadIdx.x; i < DIN * DOUT; i += 1024) {
        float4 v = *(const float4*)&Wt[i];
        int c = i / DIN, k = i % DIN;
        *(float4*)&Wl[c * WS + k] = v;
    }
    const int row0 = blockIdx.x * ROWS;
    for (int i = 4 * threadIdx.x; i < ROWS * DIN; i += 1024) {
        int r = i / DIN, k = i % DIN;
        float4 v = make_float4(0.f, 0.f, 0.f, 0.f);
        if (row0 + r < n) v = *(const float4*)&x[(long)(row0 + r) * DIN + k];
        *(float4*)&Xl[r * WS + k] = v;
    }
    __syncthreads();

    const int lrow = threadIdx.x / TPR;
    const int c0   = threadIdx.x % TPR;
    const int row  = row0 + lrow;
    if (row >= n) return;

    float acc0 = 0.f, acc1 = 0.f, acc2 = 0.f, acc3 = 0.f;
    const float* xr = &Xl[lrow * WS];
    const float* w0 = &Wl[(c0 + 0 * TPR) * WS];
    const float* w1 = &Wl[(c0 + 1 * TPR) * WS];
    const float* w2 = &Wl[(c0 + 2 * TPR) * WS];
    const float* w3 = &Wl[(c0 + 3 * TPR) * WS];

#pragma unroll 4
    for (int k = 0; k < DIN; k += 4) {
        float4 xv = *(const float4*)&xr[k];
        float4 a = *(const float4*)&w0[k];
        float4 b = *(const float4*)&w1[k];
        float4 c = *(const float4*)&w2[k];
        float4 d = *(const float4*)&w3[k];
        acc0 += xv.x * a.x + xv.y * a.y + xv.z * a.z + xv.w * a.w;
        acc1 += xv.x * b.x + xv.y * b.y + xv.z * b.z + xv.w * b.w;
        acc2 += xv.x * c.x + xv.y * c.y + xv.z * c.z + xv.w * c.w;
        acc3 += xv.x * d.x + xv.y * d.y + xv.z * d.z + xv.w * d.w;
    }

    const float ds = dis[row];
    __half* yr = &ys[(long)row * DOUT];
    yr[c0 + 0 * TPR] = __float2half(acc0 * ds);
    yr[c0 + 1 * TPR] = __float2half(acc1 * ds);
    yr[c0 + 2 * TPR] = __float2half(acc2 * ds);
    yr[c0 + 3 * TPR] = __float2half(acc3 * ds);
}

// ---------------- per-node gather (r5-validated structure), DOUT=64: 2 nodes/wave ----------------
// out[d] = dis[d] * (ys[d] + sum_edges ys[s]) + b   (dis_s folded into ys at GEMM)

template <bool RELU>
__global__ void gather2h_kernel(const int* __restrict__ rowptr, const int* __restrict__ deg,
                                const int* __restrict__ esrc, const __half* __restrict__ ys,
                                const float* __restrict__ dis, const float* __restrict__ b,
                                float* __restrict__ out, int n) {
    const int node = blockIdx.x * 8 + (threadIdx.x >> 5);
    const int c = (threadIdx.x & 31) * 2;
    if (node >= n) return;

    float2 yv = __half22float2(*(const __half2*)&ys[(long)node * 64 + c]);
    float ax = yv.x, ay = yv.y;   // self term (ys already dis-scaled)

    int k = rowptr[node];
    const int end = k + deg[node];
    for (; k + 4 <= end; k += 4) {
        int u0 = esrc[k], u1 = esrc[k + 1], u2 = esrc[k + 2], u3 = esrc[k + 3];
        float2 v0 = __half22float2(*(const __half2*)&ys[(long)u0 * 64 + c]);
        float2 v1 = __half22float2(*(const __half2*)&ys[(long)u1 * 64 + c]);
        float2 v2 = __half22float2(*(const __half2*)&ys[(long)u2 * 64 + c]);
        float2 v3 = __half22float2(*(const __half2*)&ys[(long)u3 * 64 + c]);
        ax += v0.x; ay += v0.y;
        ax += v1.x; ay += v1.y;
        ax += v2.x; ay += v2.y;
        ax += v3.x; ay += v3.y;
    }
    for (; k < end; ++k) {
        int u = esrc[k];
        float2 v = __half22float2(*(const __half2*)&ys[(long)u * 64 + c]);
        ax += v.x; ay += v.y;
    }

    const float di = dis[node];
    ax = ax * di + b[c];
    ay = ay * di + b[c + 1];
    if (RELU) { ax = fmaxf(ax, 0.0f); ay = fmaxf(ay, 0.0f); }
    *(float2*)&out[(long)node * 64 + c] = make_float2(ax, ay);
}

// ---------------- per-node gather, DOUT=32: 4 nodes/wave ----------------

template <bool RELU>
__global__ void gather4h_kernel(const int* __restrict__ rowptr, const int* __restrict__ deg,
                                const int* __restrict__ esrc, const __half* __restrict__ ys,
                                const float* __restrict__ dis, const float* __restrict__ b,
                                float* __restrict__ out, int n) {
    const int node = blockIdx.x * 16 + (threadIdx.x >> 4);
    const int c = (threadIdx.x & 15) * 2;
    if (node >= n) return;

    float2 yv = __half22float2(*(const __half2*)&ys[(long)node * 32 + c]);
    float ax = yv.x, ay = yv.y;

    int k = rowptr[node];
    const int end = k + deg[node];
    for (; k + 4 <= end; k += 4) {
        int u0 = esrc[k], u1 = esrc[k + 1], u2 = esrc[k + 2], u3 = esrc[k + 3];
        float2 v0 = __half22float2(*(const __half2*)&ys[(long)u0 * 32 + c]);
        float2 v1 = __half22float2(*(const __half2*)&ys[(long)u1 * 32 + c]);
        float2 v2 = __half22float2(*(const __half2*)&ys[(long)u2 * 32 + c]);
        float2 v3 = __half22float2(*(const __half2*)&ys[(long)u3 * 32 + c]);
        ax += v0.x; ay += v0.y;
        ax += v1.x; ay += v1.y;
        ax += v2.x; ay += v2.y;
        ax += v3.x; ay += v3.y;
    }
    for (; k < end; ++k) {
        int u = esrc[k];
        float2 v = __half22float2(*(const __half2*)&ys[(long)u * 32 + c]);
        ax += v.x; ay += v.y;
    }

    const float di = dis[node];
    ax = ax * di + b[c];
    ay = ay * di + b[c + 1];
    if (RELU) { ax = fmaxf(ax, 0.0f); ay = fmaxf(ay, 0.0f); }
    *(float2*)&out[(long)node * 32 + c] = make_float2(ax, ay);
}

// ---------------- launch ----------------

extern "C" void kernel_launch(void* const* d_in, const int* in_sizes, int n_in,
                              void* d_out, int out_size, void* d_ws, size_t ws_size,
                              hipStream_t stream) {
    const float* features = (const float*)d_in[0];
    const int*   ei       = (const int*)d_in[1];
    const float* W0 = (const float*)d_in[2];
    const float* b0 = (const float*)d_in[3];
    const float* W1 = (const float*)d_in[4];
    const float* b1 = (const float*)d_in[5];
    const float* W2 = (const float*)d_in[6];
    const float* b2 = (const float*)d_in[7];

    const int* src = ei;             // edge_index[0]
    const int* dst = ei + N_EDGES;   // edge_index[1]

    const int n = N_NODES;
    const int nb = (n + 1023) / 1024;

    // workspace layout (int slots)
    int*    H      = (int*)d_ws;                       // [0, 131072)     FBLK*NBK = 100096
    int*    bptr   = (int*)d_ws + 131072;              // [131072, 132096)
    int*    deg    = (int*)d_ws + 132096;              // [132096, 263168)
    float*  dis    = (float*)d_ws + 263168;            // [263168, 394240)
    int*    rowptr = (int*)d_ws + 394240;              // [394240, 525312)
    int*    bsums  = (int*)d_ws + 525312;              // [525312, 526336)
    int*    tmp    = (int*)d_ws + 526336;              // [526336, 2126336)   E ints
    int*    esrc   = (int*)d_ws + 2126336;             // [2126336, 3726336)  E ints
    __half* ys     = (__half*)((int*)d_ws + 3726336);  // N*64 halves = 3.2M ints
    float*  act    = (float*)d_ws + 6926336;           // N*64 floats = 6.4M ints
    float*  wt0    = (float*)d_ws + 13326336;          // 8192
    float*  wt1    = wt0 + 8192;                       // 4096
    float*  wt2    = wt1 + 4096;                       // 2048
    float*  outf   = (float*)d_out;                    // N*32 fp32

    // ---- contention-free CSR build + transposes (no memsets, no global atomics) ----
    hist_kernel<<<FBLK, 256, 0, stream>>>(dst, H);
    basescan_kernel<<<1, 1024, 0, stream>>>(H, bptr);
    binfill_kernel<<<FBLK, 256, 0, stream>>>(src, dst, H, tmp);
    degcnt_kernel<<<NBK, 256, 0, stream>>>(tmp, bptr, deg, n);
    scan_block_kernel<<<nb, 256, 0, stream>>>(deg, rowptr, bsums, dis, n);
    scan_sums_kernel<<<1, 128, 0, stream>>>(bsums, nb);
    add_offsets_kernel<<<(n + 255) / 256, 256, 0, stream>>>(rowptr, bsums, n);
    sortfin_kernel<<<NBK, 256, 0, stream>>>(tmp, esrc, rowptr, bptr, n);
    transpose_all_kernel<<<56, 256, 0, stream>>>(W0, W1, W2, wt0, wt1, wt2);

    // ---- layer 0: 128 -> 64, ReLU ----
    gemm_kernel<128, 64><<<(n + 15) / 16, 256, 0, stream>>>(features, wt0, dis, ys, n);
    gather2h_kernel<true><<<(n + 7) / 8, 256, 0, stream>>>(rowptr, deg, esrc, ys, dis, b0, act, n);

    // ---- layer 1: 64 -> 64, ReLU ----
    gemm_kernel<64, 64><<<(n + 15) / 16, 256, 0, stream>>>(act, wt1, dis, ys, n);
    gather2h_kernel<true><<<(n + 7) / 8, 256, 0, stream>>>(rowptr, deg, esrc, ys, dis, b1, act, n);

    // ---- layer 2: 64 -> 32, no ReLU ----
    gemm_kernel<64, 32><<<(n + 31) / 32, 256, 0, stream>>>(act, wt2, dis, ys, n);
    gather4h_kernel<false><<<(n + 15) / 16, 256, 0, stream>>>(rowptr, deg, esrc, ys, dis, b2, outf, n);
}

// Round 10
// 339.021 us; speedup vs baseline: 2.4033x; 1.1033x over previous
//
#include <hip/hip_runtime.h>
#include <hip/hip_fp16.h>

#define N_NODES 100000
#define N_EDGES 1600000
#define NPB 128                                   // nodes per dst-bucket
#define NBK ((N_NODES + NPB - 1) / NPB)           // 782 buckets
#define FBLK 128                                  // fill blocks
#define EPB ((N_EDGES + FBLK - 1) / FBLK)         // 12500 edges per fill block
#define CAP 4096                                  // LDS capacity per bucket (mean 2046, sigma ~45)

// ---------------- pass 1: per-block bucket histograms (validated r9) ----------------

__global__ void __launch_bounds__(256) hist_kernel(const int* __restrict__ dst, int* __restrict__ H) {
    __shared__ int h[NBK];
    for (int i = threadIdx.x; i < NBK; i += 256) h[i] = 0;
    __syncthreads();
    const int e0 = blockIdx.x * EPB;
    const int e1 = min(e0 + EPB, N_EDGES);
    for (int e = e0 + threadIdx.x; e < e1; e += 256) atomicAdd(&h[dst[e] >> 7], 1);
    __syncthreads();
    for (int i = threadIdx.x; i < NBK; i += 256) H[blockIdx.x * NBK + i] = h[i];
}

// ---------------- pass 2a: per-bucket column scan over the 128 blocks (parallel) ----------------

__global__ void __launch_bounds__(256) colscan_kernel(int* __restrict__ H, int* __restrict__ btot) {
    const int t = blockIdx.x * 256 + threadIdx.x;
    if (t >= NBK) return;
    int run = 0;
    for (int k = 0; k < FBLK; ++k) {
        int idx = k * NBK + t;
        int h = H[idx];
        H[idx] = run;           // exclusive over blocks, within bucket
        run += h;
    }
    btot[t] = run;
}

// ---------------- pass 2b: scan bucket totals -> bucket bases + bptr ----------------

__global__ void __launch_bounds__(1024) bucketscan_kernel(const int* __restrict__ btot,
                                                          int* __restrict__ bbase, int* __restrict__ bptr) {
    __shared__ int sh[1024];
    const int t = threadIdx.x;
    int v = (t < NBK) ? btot[t] : 0;
    sh[t] = v;
    __syncthreads();
    for (int off = 1; off < 1024; off <<= 1) {
        int u = (t >= off) ? sh[t - off] : 0;
        __syncthreads();
        sh[t] += u;
        __syncthreads();
    }
    if (t < NBK) { int e = sh[t] - v; bbase[t] = e; bptr[t] = e; }
    if (t == 0) bptr[NBK] = N_EDGES;
}

// ---------------- pass 3: bin edges by bucket (LDS cursors, bucket base folded in) ----------------

__global__ void __launch_bounds__(256) binfill_kernel(const int* __restrict__ src, const int* __restrict__ dst,
                                                      const int* __restrict__ H, const int* __restrict__ bbase,
                                                      int* __restrict__ tmp) {
    __shared__ int cur[NBK];
    const int k = blockIdx.x;
    for (int i = threadIdx.x; i < NBK; i += 256) cur[i] = H[k * NBK + i] + bbase[i];
    __syncthreads();
    const int e0 = k * EPB;
    const int e1 = min(e0 + EPB, N_EDGES);
    for (int e = e0 + threadIdx.x; e < e1; e += 256) {
        int s = src[e];
        int d = dst[e];
        int pos = atomicAdd(&cur[d >> 7], 1);      // LDS atomic only
        tmp[pos] = s | ((d & (NPB - 1)) << 20);
    }
}

// ---------------- pass 4: per-bucket count + local scan + rowptr/dis + LDS sort -> esrc ----------------

__global__ void __launch_bounds__(256) bucketfin_kernel(const int* __restrict__ tmp, const int* __restrict__ bptr,
                                                        int* __restrict__ esrc, int* __restrict__ rowptr,
                                                        float* __restrict__ dis, int n) {
    __shared__ int buf[CAP];
    __shared__ int cnt[NPB];
    __shared__ int sc[NPB];
    __shared__ int rp[NPB];
    __shared__ int fillc[NPB];
    const int b = blockIdx.x;
    const int d0 = b * NPB;
    const int nd = min(NPB, n - d0);
    const int base = bptr[b], end = bptr[b + 1];
    const int count = end - base;
    const int tid = threadIdx.x;

    for (int i = tid; i < NPB; i += 256) { cnt[i] = 0; fillc[i] = 0; }
    __syncthreads();
    for (int e = base + tid; e < end; e += 256) atomicAdd(&cnt[tmp[e] >> 20], 1);
    __syncthreads();

    // exclusive scan of cnt over 128 local nodes
    if (tid < NPB) sc[tid] = cnt[tid];
    __syncthreads();
    for (int off = 1; off < NPB; off <<= 1) {
        int v = (tid < NPB && tid >= off) ? sc[tid - off] : 0;
        __syncthreads();
        if (tid < NPB) sc[tid] += v;
        __syncthreads();
    }
    if (tid < NPB) {
        int excl = sc[tid] - cnt[tid];
        rp[tid] = excl;
        if (tid < nd) {
            rowptr[d0 + tid] = base + excl;
            dis[d0 + tid] = rsqrtf((float)cnt[tid] + 1.0f);
        }
    }
    if (b == NBK - 1 && tid == 0) rowptr[n] = N_EDGES;
    __syncthreads();

    if (count <= CAP) {
        for (int t = base + tid; t < end; t += 256) {
            int w = tmp[t];
            int ld = w >> 20;
            int pos = rp[ld] + atomicAdd(&fillc[ld], 1);
            buf[pos] = w & 0xFFFFF;
        }
        __syncthreads();
        for (int t = tid; t < count; t += 256) esrc[base + t] = buf[t];
    } else {
        // statistically unreachable fallback
        for (int t = base + tid; t < end; t += 256) {
            int w = tmp[t];
            int ld = w >> 20;
            int pos = rp[ld] + atomicAdd(&fillc[ld], 1);
            esrc[base + pos] = w & 0xFFFFF;
        }
    }
}

// ---------------- all 3 weight transposes in one launch ----------------

__global__ void transpose_all_kernel(const float* __restrict__ W0, const float* __restrict__ W1,
                                     const float* __restrict__ W2, float* __restrict__ wt0,
                                     float* __restrict__ wt1, float* __restrict__ wt2) {
    int i = blockIdx.x * blockDim.x + threadIdx.x;
    if (i < 8192)       { int k = i / 64, c = i % 64;                 wt0[c * 128 + k] = W0[i]; }
    else if (i < 12288) { int j = i - 8192;  int k = j / 64, c = j % 64; wt1[c * 64 + k] = W1[j]; }
    else if (i < 14336) { int j = i - 12288; int k = j / 32, c = j % 32; wt2[c * 64 + k] = W2[j]; }
}

// ---------------- dense GEMM, 4 rows x 4 cols per thread, K-tiled ----------------
// ys[row] = fp16(dis[row] * (x[row] @ W));  8 ds_read_b128 per 64 FMAs -> VALU-bound

template <int DIN, int DOUT>
__global__ void __launch_bounds__(256) gemm_kernel(const float* __restrict__ x,
                                                   const float* __restrict__ Wt,
                                                   const float* __restrict__ dis,
                                                   __half* __restrict__ ys, int n) {
    constexpr int TPC  = DOUT / 4;            // threads covering the col dim (4 cols each)
    constexpr int ROWS = (256 / TPC) * 4;     // rows per block (64 or 128)
    constexpr int KT   = (DIN > 64) ? 64 : DIN;
    constexpr int NKT  = DIN / KT;
    constexpr int WS   = KT + 4;              // padded stride, 16B-aligned

    __shared__ float Wl[DOUT * WS];
    __shared__ float Xl[ROWS * WS];

    const int row0 = blockIdx.x * ROWS;
    const int g    = threadIdx.x / TPC;
    const int c0   = threadIdx.x % TPC;
    const int r0   = g * 4;

    float4 acc[4];
#pragma unroll
    for (int r = 0; r < 4; ++r) acc[r] = make_float4(0.f, 0.f, 0.f, 0.f);

    for (int kt = 0; kt < NKT; ++kt) {
        const int kbase = kt * KT;
        for (int i = 4 * threadIdx.x; i < DOUT * KT; i += 1024) {
            int c = i / KT, k = i % KT;
            float4 v = *(const float4*)&Wt[c * DIN + kbase + k];
            *(float4*)&Wl[c * WS + k] = v;
        }
        for (int i = 4 * threadIdx.x; i < ROWS * KT; i += 1024) {
            int r = i / KT, k = i % KT;
            float4 v = make_float4(0.f, 0.f, 0.f, 0.f);
            if (row0 + r < n) v = *(const float4*)&x[(long)(row0 + r) * DIN + kbase + k];
            *(float4*)&Xl[r * WS + k] = v;
        }
        __syncthreads();

        const float* w0 = &Wl[(c0 + 0 * TPC) * WS];
        const float* w1 = &Wl[(c0 + 1 * TPC) * WS];
        const float* w2 = &Wl[(c0 + 2 * TPC) * WS];
        const float* w3 = &Wl[(c0 + 3 * TPC) * WS];

#pragma unroll 4
        for (int k = 0; k < KT; k += 4) {
            float4 a = *(const float4*)&w0[k];
            float4 b = *(const float4*)&w1[k];
            float4 c = *(const float4*)&w2[k];
            float4 d = *(const float4*)&w3[k];
#pragma unroll
            for (int r = 0; r < 4; ++r) {
                float4 xv = *(const float4*)&Xl[(r0 + r) * WS + k];
                acc[r].x += xv.x * a.x + xv.y * a.y + xv.z * a.z + xv.w * a.w;
                acc[r].y += xv.x * b.x + xv.y * b.y + xv.z * b.z + xv.w * b.w;
                acc[r].z += xv.x * c.x + xv.y * c.y + xv.z * c.z + xv.w * c.w;
                acc[r].w += xv.x * d.x + xv.y * d.y + xv.z * d.z + xv.w * d.w;
            }
        }
        __syncthreads();
    }

#pragma unroll
    for (int r = 0; r < 4; ++r) {
        const int row = row0 + r0 + r;
        if (row < n) {
            const float ds = dis[row];
            __half* yr = &ys[(long)row * DOUT];
            yr[c0 + 0 * TPC] = __float2half(acc[r].x * ds);
            yr[c0 + 1 * TPC] = __float2half(acc[r].y * ds);
            yr[c0 + 2 * TPC] = __float2half(acc[r].z * ds);
            yr[c0 + 3 * TPC] = __float2half(acc[r].w * ds);
        }
    }
}

// ---------------- per-node gather (r9-validated), DOUT=64: 2 nodes/wave ----------------
// out[d] = dis[d] * (ys[d] + sum_edges ys[s]) + b   (dis_s folded into ys at GEMM)

template <bool RELU>
__global__ void gather2h_kernel(const int* __restrict__ rowptr, const int* __restrict__ esrc,
                                const __half* __restrict__ ys, const float* __restrict__ dis,
                                const float* __restrict__ b, float* __restrict__ out, int n) {
    const int node = blockIdx.x * 8 + (threadIdx.x >> 5);
    const int c = (threadIdx.x & 31) * 2;
    if (node >= n) return;

    float2 yv = __half22float2(*(const __half2*)&ys[(long)node * 64 + c]);
    float ax = yv.x, ay = yv.y;   // self term (ys already dis-scaled)

    int k = rowptr[node];
    const int end = rowptr[node + 1];
    for (; k + 4 <= end; k += 4) {
        int u0 = esrc[k], u1 = esrc[k + 1], u2 = esrc[k + 2], u3 = esrc[k + 3];
        float2 v0 = __half22float2(*(const __half2*)&ys[(long)u0 * 64 + c]);
        float2 v1 = __half22float2(*(const __half2*)&ys[(long)u1 * 64 + c]);
        float2 v2 = __half22float2(*(const __half2*)&ys[(long)u2 * 64 + c]);
        float2 v3 = __half22float2(*(const __half2*)&ys[(long)u3 * 64 + c]);
        ax += v0.x; ay += v0.y;
        ax += v1.x; ay += v1.y;
        ax += v2.x; ay += v2.y;
        ax += v3.x; ay += v3.y;
    }
    for (; k < end; ++k) {
        int u = esrc[k];
        float2 v = __half22float2(*(const __half2*)&ys[(long)u * 64 + c]);
        ax += v.x; ay += v.y;
    }

    const float di = dis[node];
    ax = ax * di + b[c];
    ay = ay * di + b[c + 1];
    if (RELU) { ax = fmaxf(ax, 0.0f); ay = fmaxf(ay, 0.0f); }
    *(float2*)&out[(long)node * 64 + c] = make_float2(ax, ay);
}

// ---------------- per-node gather, DOUT=32: 4 nodes/wave ----------------

template <bool RELU>
__global__ void gather4h_kernel(const int* __restrict__ rowptr, const int* __restrict__ esrc,
                                const __half* __restrict__ ys, const float* __restrict__ dis,
                                const float* __restrict__ b, float* __restrict__ out, int n) {
    const int node = blockIdx.x * 16 + (threadIdx.x >> 4);
    const int c = (threadIdx.x & 15) * 2;
    if (node >= n) return;

    float2 yv = __half22float2(*(const __half2*)&ys[(long)node * 32 + c]);
    float ax = yv.x, ay = yv.y;

    int k = rowptr[node];
    const int end = rowptr[node + 1];
    for (; k + 4 <= end; k += 4) {
        int u0 = esrc[k], u1 = esrc[k + 1], u2 = esrc[k + 2], u3 = esrc[k + 3];
        float2 v0 = __half22float2(*(const __half2*)&ys[(long)u0 * 32 + c]);
        float2 v1 = __half22float2(*(const __half2*)&ys[(long)u1 * 32 + c]);
        float2 v2 = __half22float2(*(const __half2*)&ys[(long)u2 * 32 + c]);
        float2 v3 = __half22float2(*(const __half2*)&ys[(long)u3 * 32 + c]);
        ax += v0.x; ay += v0.y;
        ax += v1.x; ay += v1.y;
        ax += v2.x; ay += v2.y;
        ax += v3.x; ay += v3.y;
    }
    for (; k < end; ++k) {
        int u = esrc[k];
        float2 v = __half22float2(*(const __half2*)&ys[(long)u * 32 + c]);
        ax += v.x; ay += v.y;
    }

    const float di = dis[node];
    ax = ax * di + b[c];
    ay = ay * di + b[c + 1];
    if (RELU) { ax = fmaxf(ax, 0.0f); ay = fmaxf(ay, 0.0f); }
    *(float2*)&out[(long)node * 32 + c] = make_float2(ax, ay);
}

// ---------------- launch ----------------

extern "C" void kernel_launch(void* const* d_in, const int* in_sizes, int n_in,
                              void* d_out, int out_size, void* d_ws, size_t ws_size,
                              hipStream_t stream) {
    const float* features = (const float*)d_in[0];
    const int*   ei       = (const int*)d_in[1];
    const float* W0 = (const float*)d_in[2];
    const float* b0 = (const float*)d_in[3];
    const float* W1 = (const float*)d_in[4];
    const float* b1 = (const float*)d_in[5];
    const float* W2 = (const float*)d_in[6];
    const float* b2 = (const float*)d_in[7];

    const int* src = ei;             // edge_index[0]
    const int* dst = ei + N_EDGES;   // edge_index[1]

    const int n = N_NODES;

    // workspace layout (int slots)
    int*    H      = (int*)d_ws;                       // [0, 131072)      FBLK*NBK = 100096
    int*    btot   = (int*)d_ws + 131072;              // [131072, 132096)
    int*    bbase  = (int*)d_ws + 132096;              // [132096, 133120)
    int*    bptr   = (int*)d_ws + 133120;              // [133120, 135168)
    float*  dis    = (float*)d_ws + 135168;            // [135168, 266240)
    int*    rowptr = (int*)d_ws + 266240;              // [266240, 397312)  n+1 fits
    int*    tmp    = (int*)d_ws + 397312;              // [397312, 1997312)   E ints
    int*    esrc   = (int*)d_ws + 1997312;             // [1997312, 3597312)  E ints
    __half* ys     = (__half*)((int*)d_ws + 3597312);  // N*64 halves = 3.2M ints
    float*  act    = (float*)d_ws + 6797312;           // N*64 floats = 6.4M ints
    float*  wt0    = (float*)d_ws + 13197312;          // 8192
    float*  wt1    = wt0 + 8192;                       // 4096
    float*  wt2    = wt1 + 4096;                       // 2048
    float*  outf   = (float*)d_out;                    // N*32 fp32

    // ---- contention-free CSR build + transposes (no memsets, no global atomics) ----
    hist_kernel<<<FBLK, 256, 0, stream>>>(dst, H);
    colscan_kernel<<<(NBK + 255) / 256, 256, 0, stream>>>(H, btot);
    bucketscan_kernel<<<1, 1024, 0, stream>>>(btot, bbase, bptr);
    binfill_kernel<<<FBLK, 256, 0, stream>>>(src, dst, H, bbase, tmp);
    bucketfin_kernel<<<NBK, 256, 0, stream>>>(tmp, bptr, esrc, rowptr, dis, n);
    transpose_all_kernel<<<56, 256, 0, stream>>>(W0, W1, W2, wt0, wt1, wt2);

    // ---- layer 0: 128 -> 64, ReLU ----
    gemm_kernel<128, 64><<<(n + 63) / 64, 256, 0, stream>>>(features, wt0, dis, ys, n);
    gather2h_kernel<true><<<(n + 7) / 8, 256, 0, stream>>>(rowptr, esrc, ys, dis, b0, act, n);

    // ---- layer 1: 64 -> 64, ReLU ----
    gemm_kernel<64, 64><<<(n + 63) / 64, 256, 0, stream>>>(act, wt1, dis, ys, n);
    gather2h_kernel<true><<<(n + 7) / 8, 256, 0, stream>>>(rowptr, esrc, ys, dis, b1, act, n);

    // ---- layer 2: 64 -> 32, no ReLU ----
    gemm_kernel<64, 32><<<(n + 127) / 128, 256, 0, stream>>>(act, wt2, dis, ys, n);
    gather4h_kernel<false><<<(n + 15) / 16, 256, 0, stream>>>(rowptr, esrc, ys, dis, b2, outf, n);
}